// Round 1
// baseline (4432.821 us; speedup 1.0000x reference)
//
#include <hip/hip_runtime.h>
#include <math.h>

typedef __bf16 bf16_t;
typedef __bf16 bf16x8 __attribute__((ext_vector_type(8)));
typedef float f32x4 __attribute__((ext_vector_type(4)));

#define BATCH   32
#define SEQ     1024
#define DMODEL  1024
#define NHEADS  16
#define DIMH    64
#define TEXTLEN 77
#define IMGLEN  256
#define CTXLEN  333
#define MAXREL  1024

// ---------------------------------------------------------------- converts
__global__ __launch_bounds__(256) void k_cvt_x(const float* __restrict__ in,
                                               bf16_t* __restrict__ out) {
  size_t idx = ((size_t)blockIdx.x * blockDim.x + threadIdx.x) * 8;
  float4 a = *(const float4*)(in + idx);
  float4 b = *(const float4*)(in + idx + 4);
  bf16x8 o;
  o[0] = (bf16_t)a.x; o[1] = (bf16_t)a.y; o[2] = (bf16_t)a.z; o[3] = (bf16_t)a.w;
  o[4] = (bf16_t)b.x; o[5] = (bf16_t)b.y; o[6] = (bf16_t)b.z; o[7] = (bf16_t)b.w;
  *(bf16x8*)(out + idx) = o;
}

// context (B,333,D) f32 -> compact bf16 text rows (b*77+t) and image rows (b*256+u)
__global__ __launch_bounds__(128) void k_cvt_ctx(const float* __restrict__ ctx,
                                                 bf16_t* __restrict__ ctxT,
                                                 bf16_t* __restrict__ ctxI) {
  int row = blockIdx.x;                  // 0 .. 32*333-1
  int b = row / CTXLEN, t = row - b * CTXLEN;
  const float* src = ctx + (size_t)row * DMODEL + threadIdx.x * 8;
  bf16_t* dst = (t < TEXTLEN)
      ? ctxT + ((size_t)(b * TEXTLEN + t)) * DMODEL + threadIdx.x * 8
      : ctxI + ((size_t)(b * IMGLEN + (t - TEXTLEN))) * DMODEL + threadIdx.x * 8;
  float4 a = *(const float4*)(src);
  float4 c = *(const float4*)(src + 4);
  bf16x8 o;
  o[0] = (bf16_t)a.x; o[1] = (bf16_t)a.y; o[2] = (bf16_t)a.z; o[3] = (bf16_t)a.w;
  o[4] = (bf16_t)c.x; o[5] = (bf16_t)c.y; o[6] = (bf16_t)c.z; o[7] = (bf16_t)c.w;
  *(bf16x8*)dst = o;
}

// W (K x N) f32 row-major -> WT (N x K) bf16 row-major
__global__ void k_transpose_w(const float* __restrict__ W, bf16_t* __restrict__ WT) {
  __shared__ float tile[32][33];
  int x = threadIdx.x, y = threadIdx.y;          // block (32,8)
  int n0 = blockIdx.x * 32, k0 = blockIdx.y * 32;
  #pragma unroll
  for (int r = 0; r < 32; r += 8) {
    tile[y + r][x] = W[(size_t)(k0 + y + r) * DMODEL + n0 + x];
  }
  __syncthreads();
  #pragma unroll
  for (int r = 0; r < 32; r += 8) {
    WT[(size_t)(n0 + y + r) * DMODEL + k0 + x] = (bf16_t)tile[x][y + r];
  }
}

// ---------------------------------------------------------------- GEMM
typedef __attribute__((address_space(1))) void gvoid;
typedef __attribute__((address_space(3))) void svoid;

__device__ __forceinline__ void async_ld16(const void* g, void* l) {
  __builtin_amdgcn_global_load_lds((gvoid*)g, (svoid*)l, 16, 0, 0);
}

// C = A(MxK bf16) * B(KxN) with B given transposed (BT: N x K bf16).
// STORE: 0 -> bf16, 1 -> f32, 2 -> f32 + bias
template<int STORE>
__global__ __launch_bounds__(256) void k_gemm(
    const bf16_t* __restrict__ A, const bf16_t* __restrict__ BT,
    void* __restrict__ Cout, const float* __restrict__ bias,
    int M, int N, int K)
{
  __shared__ __align__(16) bf16_t lds_a[128 * 32];
  __shared__ __align__(16) bf16_t lds_b[128 * 32];
  const int tid = threadIdx.x;
  const int wid = tid >> 6, lane = tid & 63;
  const int brow = blockIdx.x * 128, bcol = blockIdx.y * 128;
  const int wr = (wid >> 1) * 64, wc = (wid & 1) * 64;
  const int lhi = lane >> 4, llo = lane & 15;

  f32x4 acc[4][4];
  #pragma unroll
  for (int m = 0; m < 4; ++m) {
    #pragma unroll
    for (int n = 0; n < 4; ++n) {
      acc[m][n] = (f32x4){0.f, 0.f, 0.f, 0.f};
    }
  }

  for (int kk = 0; kk < K; kk += 32) {
    #pragma unroll
    for (int c = 0; c < 2; ++c) {
      const int e = wid * 512 + c * 2048 + lane * 8;   // bf16 element in 128x32 tile
      const int row = e >> 5, col = e & 31;
      async_ld16(A  + (size_t)(brow + row) * K + kk + col, &lds_a[wid * 512 + c * 2048]);
      async_ld16(BT + (size_t)(bcol + row) * K + kk + col, &lds_b[wid * 512 + c * 2048]);
    }
    __syncthreads();
    bf16x8 af[4], bfv[4];
    #pragma unroll
    for (int m = 0; m < 4; ++m) {
      af[m] = *(const bf16x8*)&lds_a[(wr + m * 16 + llo) * 32 + lhi * 8];
    }
    #pragma unroll
    for (int n = 0; n < 4; ++n) {
      bfv[n] = *(const bf16x8*)&lds_b[(wc + n * 16 + llo) * 32 + lhi * 8];
    }
    #pragma unroll
    for (int m = 0; m < 4; ++m) {
      #pragma unroll
      for (int n = 0; n < 4; ++n) {
        acc[m][n] = __builtin_amdgcn_mfma_f32_16x16x32_bf16(af[m], bfv[n], acc[m][n], 0, 0, 0);
      }
    }
    __syncthreads();
  }

  #pragma unroll
  for (int m = 0; m < 4; ++m) {
    #pragma unroll
    for (int n = 0; n < 4; ++n) {
      const int gc = bcol + wc + n * 16 + llo;
      #pragma unroll
      for (int r = 0; r < 4; ++r) {
        const int gr = brow + wr + m * 16 + lhi * 4 + r;
        float v = acc[m][n][r];
        if constexpr (STORE == 0)      ((bf16_t*)Cout)[(size_t)gr * N + gc] = (bf16_t)v;
        else if constexpr (STORE == 1) ((float*)Cout)[(size_t)gr * N + gc] = v;
        else                           ((float*)Cout)[(size_t)gr * N + gc] = v + bias[gc];
      }
    }
  }
}

// ---------------------------------------------------------------- attention
__device__ __forceinline__ float dot_kr(const float* __restrict__ q,
                                        const float* __restrict__ kj,
                                        const float* __restrict__ rj) {
  float s0 = 0.f, s1 = 0.f, s2 = 0.f, s3 = 0.f;
  #pragma unroll
  for (int d4 = 0; d4 < 16; ++d4) {
    float4 kv = *(const float4*)(kj + d4 * 4);
    float4 rr = *(const float4*)(rj + d4 * 4);
    s0 += q[d4 * 4 + 0] * (kv.x + rr.x);
    s1 += q[d4 * 4 + 1] * (kv.y + rr.y);
    s2 += q[d4 * 4 + 2] * (kv.z + rr.z);
    s3 += q[d4 * 4 + 3] * (kv.w + rr.w);
  }
  return (s0 + s1) + (s2 + s3);
}

__device__ __forceinline__ float dot_k(const float* __restrict__ q,
                                       const float* __restrict__ kj) {
  float s0 = 0.f, s1 = 0.f, s2 = 0.f, s3 = 0.f;
  #pragma unroll
  for (int d4 = 0; d4 < 16; ++d4) {
    float4 kv = *(const float4*)(kj + d4 * 4);
    s0 += q[d4 * 4 + 0] * kv.x;
    s1 += q[d4 * 4 + 1] * kv.y;
    s2 += q[d4 * 4 + 2] * kv.z;
    s3 += q[d4 * 4 + 3] * kv.w;
  }
  return (s0 + s1) + (s2 + s3);
}

__global__ __launch_bounds__(256) void k_attn(
    const bf16_t* __restrict__ Qb,
    const float* __restrict__ Kb,  const float* __restrict__ Vb,
    const float* __restrict__ Kip, const float* __restrict__ Vip,
    const float* __restrict__ relk, const float* __restrict__ relv,
    const float* __restrict__ alpha,
    bf16_t* __restrict__ Ob)
{
  const int t = threadIdx.x;
  const int bh = blockIdx.y;
  const int b = bh >> 4, h = bh & 15;
  const int i = blockIdx.x * 256 + t;
  const float scale = 0.125f;

  float q[64];
  {
    const bf16_t* qp = Qb + ((size_t)(b * SEQ + i)) * DMODEL + h * DIMH;
    #pragma unroll
    for (int c = 0; c < 8; ++c) {
      bf16x8 v = *(const bf16x8*)(qp + c * 8);
      #pragma unroll
      for (int e = 0; e < 8; ++e) q[c * 8 + e] = (float)v[e];
    }
  }

  float acc[64];
  #pragma unroll
  for (int d = 0; d < 64; ++d) acc[d] = 0.f;

  // ---- text attention with relative position terms folded in ----
  {
    const float* kb  = Kb + (size_t)(b * TEXTLEN) * DMODEL + h * DIMH;
    const float* vb  = Vb + (size_t)(b * TEXTLEN) * DMODEL + h * DIMH;
    const float* rkb = relk + (size_t)(MAXREL - i) * DIMH;   // row for j=0
    const float* rvb = relv + (size_t)(MAXREL - i) * DIMH;
    float m = -1e30f, s = 0.f;
    for (int j = 0; j < TEXTLEN; ++j) {
      float sim = dot_kr(q, kb + (size_t)j * DMODEL, rkb + j * DIMH) * scale;
      float nm = fmaxf(m, sim);
      s = s * __expf(m - nm) + __expf(sim - nm);
      m = nm;
    }
    for (int j = 0; j < TEXTLEN; ++j) {
      float sim = dot_kr(q, kb + (size_t)j * DMODEL, rkb + j * DIMH) * scale;
      float p = __expf(sim - m);
      const float* vj  = vb + (size_t)j * DMODEL;
      const float* rvj = rvb + j * DIMH;
      #pragma unroll
      for (int d4 = 0; d4 < 16; ++d4) {
        float4 vv = *(const float4*)(vj + d4 * 4);
        float4 rr = *(const float4*)(rvj + d4 * 4);
        acc[d4 * 4 + 0] += p * (vv.x + rr.x);
        acc[d4 * 4 + 1] += p * (vv.y + rr.y);
        acc[d4 * 4 + 2] += p * (vv.z + rr.z);
        acc[d4 * 4 + 3] += p * (vv.w + rr.w);
      }
    }
    float inv = 1.f / s;
    #pragma unroll
    for (int d = 0; d < 64; ++d) acc[d] *= inv;
  }

  // ---- IP-adapter (image) attention ----
  {
    const float* kb = Kip + (size_t)(b * IMGLEN) * DMODEL + h * DIMH;
    const float* vb = Vip + (size_t)(b * IMGLEN) * DMODEL + h * DIMH;
    float m = -1e30f, s = 0.f;
    for (int j = 0; j < IMGLEN; ++j) {
      float sim = dot_k(q, kb + (size_t)j * DMODEL) * scale;
      float nm = fmaxf(m, sim);
      s = s * __expf(m - nm) + __expf(sim - nm);
      m = nm;
    }
    float coef = (tanhf(alpha[0]) + 1.0f) / s;   // IMG_SCALE = 1.0
    for (int j = 0; j < IMGLEN; ++j) {
      float sim = dot_k(q, kb + (size_t)j * DMODEL) * scale;
      float p = __expf(sim - m) * coef;
      const float* vj = vb + (size_t)j * DMODEL;
      #pragma unroll
      for (int d4 = 0; d4 < 16; ++d4) {
        float4 vv = *(const float4*)(vj + d4 * 4);
        acc[d4 * 4 + 0] += p * vv.x;
        acc[d4 * 4 + 1] += p * vv.y;
        acc[d4 * 4 + 2] += p * vv.z;
        acc[d4 * 4 + 3] += p * vv.w;
      }
    }
  }

  bf16_t* op = Ob + ((size_t)(b * SEQ + i)) * DMODEL + h * DIMH;
  #pragma unroll
  for (int c = 0; c < 8; ++c) {
    bf16x8 o;
    #pragma unroll
    for (int e = 0; e < 8; ++e) o[e] = (bf16_t)acc[c * 8 + e];
    *(bf16x8*)(op + c * 8) = o;
  }
}

// ---------------------------------------------------------------- launch
extern "C" void kernel_launch(void* const* d_in, const int* in_sizes, int n_in,
                              void* d_out, int out_size, void* d_ws, size_t ws_size,
                              hipStream_t stream)
{
  const float* x     = (const float*)d_in[0];
  const float* ctx   = (const float*)d_in[1];
  const float* W_q   = (const float*)d_in[2];
  const float* W_k   = (const float*)d_in[3];
  const float* W_v   = (const float*)d_in[4];
  const float* W_kip = (const float*)d_in[5];
  const float* W_vip = (const float*)d_in[6];
  const float* rel_k = (const float*)d_in[7];
  const float* rel_v = (const float*)d_in[8];
  const float* W_out = (const float*)d_in[9];
  const float* b_out = (const float*)d_in[10];
  const float* alpha = (const float*)d_in[11];

  // workspace carve (bytes)
  char* ws = (char*)d_ws;
  bf16_t* Xb   = (bf16_t*)(ws + 0);            // 32768x1024 bf16 (64MB), reused as Ob
  bf16_t* Qb   = (bf16_t*)(ws + 67108864);     // 32768x1024 bf16 (64MB)
  bf16_t* CtxT = (bf16_t*)(ws + 134217728);    // 2560x1024  bf16 (5MB, 2464 valid rows)
  bf16_t* CtxI = (bf16_t*)(ws + 139460608);    // 8192x1024  bf16 (16MB)
  bf16_t* WTs  = (bf16_t*)(ws + 156237824);    // 6 x 1024x1024 bf16 (12MB)
  bf16_t* WqT   = WTs + 0 * 1048576;
  bf16_t* WkT   = WTs + 1 * 1048576;
  bf16_t* WvT   = WTs + 2 * 1048576;
  bf16_t* WkipT = WTs + 3 * 1048576;
  bf16_t* WvipT = WTs + 4 * 1048576;
  bf16_t* WoutT = WTs + 5 * 1048576;
  bf16_t* Ob = Xb;

  // K/V buffers live in d_out scratch (dead before final GEMM writes d_out)
  char* dob = (char*)d_out;
  float* Kip = (float*)(dob + 0);          // 8192x1024 f32 (32MB)
  float* Vip = (float*)(dob + 33554432);   // 32MB
  float* Kb  = (float*)(dob + 67108864);   // 2560x1024 f32 (10MB)
  float* Vb  = (float*)(dob + 77594624);   // 10MB

  // 1) converts / transposes
  k_cvt_x<<<16384, 256, 0, stream>>>(x, Xb);
  k_cvt_ctx<<<BATCH * CTXLEN, 128, 0, stream>>>(ctx, CtxT, CtxI);
  dim3 tb(32, 8), tg(32, 32);
  k_transpose_w<<<tg, tb, 0, stream>>>(W_q,   WqT);
  k_transpose_w<<<tg, tb, 0, stream>>>(W_k,   WkT);
  k_transpose_w<<<tg, tb, 0, stream>>>(W_v,   WvT);
  k_transpose_w<<<tg, tb, 0, stream>>>(W_kip, WkipT);
  k_transpose_w<<<tg, tb, 0, stream>>>(W_vip, WvipT);
  k_transpose_w<<<tg, tb, 0, stream>>>(W_out, WoutT);

  // 2) projections
  k_gemm<0><<<dim3(256, 8), 256, 0, stream>>>(Xb,   WqT,   (void*)Qb,  nullptr, 32768, 1024, 1024);
  k_gemm<1><<<dim3(20, 8),  256, 0, stream>>>(CtxT, WkT,   (void*)Kb,  nullptr, 2560,  1024, 1024);
  k_gemm<1><<<dim3(20, 8),  256, 0, stream>>>(CtxT, WvT,   (void*)Vb,  nullptr, 2560,  1024, 1024);
  k_gemm<1><<<dim3(64, 8),  256, 0, stream>>>(CtxI, WkipT, (void*)Kip, nullptr, 8192,  1024, 1024);
  k_gemm<1><<<dim3(64, 8),  256, 0, stream>>>(CtxI, WvipT, (void*)Vip, nullptr, 8192,  1024, 1024);

  // 3) fused text(+rel) and IP attention -> Ob (bf16)
  k_attn<<<dim3(4, 512), 256, 0, stream>>>(Qb, Kb, Vb, Kip, Vip, rel_k, rel_v, alpha, Ob);

  // 4) output projection + bias -> d_out (f32)
  k_gemm<2><<<dim3(256, 8), 256, 0, stream>>>(Ob, WoutT, d_out, b_out, 32768, 1024, 1024);
}

// Round 2
// 817.889 us; speedup vs baseline: 5.4198x; 5.4198x over previous
//
#include <hip/hip_runtime.h>
#include <math.h>

typedef __bf16 bf16_t;
typedef __bf16 bf16x8 __attribute__((ext_vector_type(8)));
typedef float f32x4 __attribute__((ext_vector_type(4)));

#define BATCH   32
#define SEQ     1024
#define DMODEL  1024
#define NHEADS  16
#define DIMH    64
#define TEXTLEN 77
#define IMGLEN  256
#define CTXLEN  333
#define MAXREL  1024

#define MFMA16(a,b,c) __builtin_amdgcn_mfma_f32_16x16x32_bf16(a, b, c, 0, 0, 0)
#define SCALE_LOG2E 0.1803368809f   // 0.125 * log2(e)

// ---------------------------------------------------------------- converts
__global__ __launch_bounds__(256) void k_cvt_x(const float* __restrict__ in,
                                               bf16_t* __restrict__ out) {
  size_t idx = ((size_t)blockIdx.x * blockDim.x + threadIdx.x) * 8;
  float4 a = *(const float4*)(in + idx);
  float4 b = *(const float4*)(in + idx + 4);
  bf16x8 o;
  o[0] = (bf16_t)a.x; o[1] = (bf16_t)a.y; o[2] = (bf16_t)a.z; o[3] = (bf16_t)a.w;
  o[4] = (bf16_t)b.x; o[5] = (bf16_t)b.y; o[6] = (bf16_t)b.z; o[7] = (bf16_t)b.w;
  *(bf16x8*)(out + idx) = o;
}

__global__ __launch_bounds__(128) void k_cvt_ctx(const float* __restrict__ ctx,
                                                 bf16_t* __restrict__ ctxT,
                                                 bf16_t* __restrict__ ctxI) {
  int row = blockIdx.x;
  int b = row / CTXLEN, t = row - b * CTXLEN;
  const float* src = ctx + (size_t)row * DMODEL + threadIdx.x * 8;
  bf16_t* dst = (t < TEXTLEN)
      ? ctxT + ((size_t)(b * TEXTLEN + t)) * DMODEL + threadIdx.x * 8
      : ctxI + ((size_t)(b * IMGLEN + (t - TEXTLEN))) * DMODEL + threadIdx.x * 8;
  float4 a = *(const float4*)(src);
  float4 c = *(const float4*)(src + 4);
  bf16x8 o;
  o[0] = (bf16_t)a.x; o[1] = (bf16_t)a.y; o[2] = (bf16_t)a.z; o[3] = (bf16_t)a.w;
  o[4] = (bf16_t)c.x; o[5] = (bf16_t)c.y; o[6] = (bf16_t)c.z; o[7] = (bf16_t)c.w;
  *(bf16x8*)dst = o;
}

__global__ void k_transpose_w(const float* __restrict__ W, bf16_t* __restrict__ WT) {
  __shared__ float tile[32][33];
  int x = threadIdx.x, y = threadIdx.y;
  int n0 = blockIdx.x * 32, k0 = blockIdx.y * 32;
  #pragma unroll
  for (int r = 0; r < 32; r += 8)
    tile[y + r][x] = W[(size_t)(k0 + y + r) * DMODEL + n0 + x];
  __syncthreads();
  #pragma unroll
  for (int r = 0; r < 32; r += 8)
    WT[(size_t)(n0 + y + r) * DMODEL + k0 + x] = (bf16_t)tile[x][y + r];
}

// Rkb[u][d] = bf16(rel_k[u+1][d]), u in [0,2048)
__global__ __launch_bounds__(256) void k_cvt_relk(const float* __restrict__ relk,
                                                  bf16_t* __restrict__ Rkb) {
  int idx = blockIdx.x * 256 + threadIdx.x;     // 16384 threads
  int u = idx >> 3, d0 = (idx & 7) * 8;
  const float* s = relk + (size_t)(u + 1) * DIMH + d0;
  float4 a = *(const float4*)s;
  float4 b = *(const float4*)(s + 4);
  bf16x8 o;
  o[0] = (bf16_t)a.x; o[1] = (bf16_t)a.y; o[2] = (bf16_t)a.z; o[3] = (bf16_t)a.w;
  o[4] = (bf16_t)b.x; o[5] = (bf16_t)b.y; o[6] = (bf16_t)b.z; o[7] = (bf16_t)b.w;
  *(bf16x8*)(Rkb + (size_t)u * DIMH + d0) = o;
}

// RvT[d][u] = bf16(rel_v[u+1][d]) — transposed table [64][2048]
__global__ __launch_bounds__(256) void k_cvt_relvT(const float* __restrict__ relv,
                                                   bf16_t* __restrict__ RvT) {
  int idx = blockIdx.x * 256 + threadIdx.x;     // 16384 threads
  int d = idx >> 8, u0 = (idx & 255) * 8;
  bf16x8 o;
  #pragma unroll
  for (int e = 0; e < 8; ++e)
    o[e] = (bf16_t)relv[(size_t)(u0 + e + 1) * DIMH + d];
  *(bf16x8*)(RvT + (size_t)d * 2048 + u0) = o;
}

// ---------------------------------------------------------------- GEMM
typedef __attribute__((address_space(1))) void gvoid;
typedef __attribute__((address_space(3))) void svoid;

__device__ __forceinline__ void async_ld16(const void* g, void* l) {
  __builtin_amdgcn_global_load_lds((gvoid*)g, (svoid*)l, 16, 0, 0);
}

// C = A(MxK bf16) * BT(NxK bf16)^T. STORE: 0 -> bf16, 2 -> f32 + bias
template<int STORE>
__global__ __launch_bounds__(256) void k_gemm(
    const bf16_t* __restrict__ A, const bf16_t* __restrict__ BT,
    void* __restrict__ Cout, const float* __restrict__ bias,
    int M, int N, int K)
{
  __shared__ __align__(16) bf16_t lds_a[128 * 32];
  __shared__ __align__(16) bf16_t lds_b[128 * 32];
  const int tid = threadIdx.x;
  const int wid = tid >> 6, lane = tid & 63;
  const int brow = blockIdx.x * 128, bcol = blockIdx.y * 128;
  const int wr = (wid >> 1) * 64, wc = (wid & 1) * 64;
  const int lhi = lane >> 4, llo = lane & 15;

  f32x4 acc[4][4];
  #pragma unroll
  for (int m = 0; m < 4; ++m)
    #pragma unroll
    for (int n = 0; n < 4; ++n)
      acc[m][n] = (f32x4){0.f, 0.f, 0.f, 0.f};

  for (int kk = 0; kk < K; kk += 32) {
    #pragma unroll
    for (int c = 0; c < 2; ++c) {
      const int e = wid * 512 + c * 2048 + lane * 8;
      const int row = e >> 5, col = e & 31;
      async_ld16(A  + (size_t)(brow + row) * K + kk + col, &lds_a[wid * 512 + c * 2048]);
      async_ld16(BT + (size_t)(bcol + row) * K + kk + col, &lds_b[wid * 512 + c * 2048]);
    }
    __syncthreads();
    bf16x8 af[4], bfv[4];
    #pragma unroll
    for (int m = 0; m < 4; ++m)
      af[m] = *(const bf16x8*)&lds_a[(wr + m * 16 + llo) * 32 + lhi * 8];
    #pragma unroll
    for (int n = 0; n < 4; ++n)
      bfv[n] = *(const bf16x8*)&lds_b[(wc + n * 16 + llo) * 32 + lhi * 8];
    #pragma unroll
    for (int m = 0; m < 4; ++m)
      #pragma unroll
      for (int n = 0; n < 4; ++n)
        acc[m][n] = MFMA16(af[m], bfv[n], acc[m][n]);
    __syncthreads();
  }

  #pragma unroll
  for (int m = 0; m < 4; ++m)
    #pragma unroll
    for (int n = 0; n < 4; ++n) {
      const int gc = bcol + wc + n * 16 + llo;
      #pragma unroll
      for (int r = 0; r < 4; ++r) {
        const int gr = brow + wr + m * 16 + lhi * 4 + r;
        float v = acc[m][n][r];
        if constexpr (STORE == 0) ((bf16_t*)Cout)[(size_t)gr * N + gc] = (bf16_t)v;
        else                      ((float*)Cout)[(size_t)gr * N + gc] = v + bias[gc];
      }
    }
}

// ---------------------------------------------------------------- V transpose
// V (rows b*RPB+u, cols h*64+d) -> Vt[bh][64][OUTC] with Vt[bh][d][u]
template<int RPB, int OUTC>
__global__ __launch_bounds__(256) void k_vtrans(const bf16_t* __restrict__ V,
                                                bf16_t* __restrict__ Vt) {
  __shared__ bf16_t tile[64][72];
  const int nt = (OUTC + 63) / 64;
  const int u0 = (blockIdx.x % nt) * 64;
  const int bh = blockIdx.x / nt;
  const int b = bh >> 4, h = bh & 15;
  const int tid = threadIdx.x;
  const int ur = tid >> 2, cg = (tid & 3) * 16;
  {
    const bf16_t* src = V + ((size_t)(b * RPB + u0 + ur)) * DMODEL + h * DIMH + cg;
    *(bf16x8*)&tile[ur][cg] = *(const bf16x8*)src;
    *(bf16x8*)&tile[ur][cg + 8] = *(const bf16x8*)(src + 8);
  }
  __syncthreads();
  bf16x8 o0, o1;
  #pragma unroll
  for (int e = 0; e < 8; ++e) { o0[e] = tile[cg + e][ur]; o1[e] = tile[cg + 8 + e][ur]; }
  bf16_t* dst = Vt + (size_t)bh * 64 * OUTC + (size_t)ur * OUTC + u0 + cg;
  if (u0 + cg + 8 <= OUTC)  *(bf16x8*)dst = o0;
  if (u0 + cg + 16 <= OUTC) *(bf16x8*)(dst + 8) = o1;
}

// ---------------------------------------------------------------- flash attn
// grid (16 tiles, 512 bh), 256 threads = 4 independent waves, 16 query rows each.
__global__ __launch_bounds__(256) void k_flash(
    const bf16_t* __restrict__ Qb,    // [32768][1024]
    const bf16_t* __restrict__ Kb,    // [2560][1024]  rows b*77+j
    const bf16_t* __restrict__ Kip,   // [8192][1024]  rows b*256+u
    const bf16_t* __restrict__ Vt,    // [512][64][80]
    const bf16_t* __restrict__ Vipt,  // [512][64][256]
    const bf16_t* __restrict__ Rkb,   // [2048][64]  row u = rel_k[u+1]
    const bf16_t* __restrict__ RvT,   // [64][2048]  RvT[d][u] = rel_v[u+1][d]
    const float* __restrict__ alpha,
    bf16_t* __restrict__ Ob)          // [32768][1024]
{
  // per-wave union buffer: max(16*148 f32 = 9472 B, 16*264 bf16 = 8448 B)
  __shared__ __align__(16) char u_lds[4][9472];
  const int tid = threadIdx.x;
  const int w = tid >> 6, lane = tid & 63;
  const int c = lane & 15, g = lane >> 4;
  const int i0 = blockIdx.x * 64;
  const int bh = blockIdx.y;
  const int b = bh >> 4, h = bh & 15;
  const int iw = i0 + w * 16;

  bf16_t* p_lds = (bf16_t*)u_lds[w];
  float*  t_lds = (float*)u_lds[w];

  // Q A-fragments (row = c, k-chunks at g*8)
  bf16x8 qa[2];
  {
    const bf16_t* qp = Qb + ((size_t)(b * SEQ + iw + c)) * DMODEL + h * DIMH + g * 8;
    qa[0] = *(const bf16x8*)qp;
    qa[1] = *(const bf16x8*)(qp + 32);
  }

  // ================= image (IP-adapter) attention =================
  f32x4 oi[4];
  float inv_si[4];
  {
    f32x4 s2[16];
    #pragma unroll
    for (int n = 0; n < 16; ++n) s2[n] = (f32x4){0.f, 0.f, 0.f, 0.f};
    const bf16_t* kp = Kip + ((size_t)(b * IMGLEN + c)) * DMODEL + h * DIMH + g * 8;
    #pragma unroll
    for (int n = 0; n < 16; ++n) {
      bf16x8 b0 = *(const bf16x8*)(kp + (size_t)n * 16 * DMODEL);
      bf16x8 b1 = *(const bf16x8*)(kp + (size_t)n * 16 * DMODEL + 32);
      s2[n] = MFMA16(qa[0], b0, s2[n]);
      s2[n] = MFMA16(qa[1], b1, s2[n]);
    }
    float rmax[4], rsum[4];
    #pragma unroll
    for (int r = 0; r < 4; ++r) {
      float m = s2[0][r];
      #pragma unroll
      for (int n = 1; n < 16; ++n) m = fmaxf(m, s2[n][r]);
      m = fmaxf(m, __shfl_xor(m, 1));
      m = fmaxf(m, __shfl_xor(m, 2));
      m = fmaxf(m, __shfl_xor(m, 4));
      m = fmaxf(m, __shfl_xor(m, 8));
      rmax[r] = m;
    }
    #pragma unroll
    for (int r = 0; r < 4; ++r) {
      float s = 0.f;
      #pragma unroll
      for (int n = 0; n < 16; ++n) {
        float p = exp2f((s2[n][r] - rmax[r]) * SCALE_LOG2E);
        s2[n][r] = p;
        s += p;
      }
      s += __shfl_xor(s, 1);
      s += __shfl_xor(s, 2);
      s += __shfl_xor(s, 4);
      s += __shfl_xor(s, 8);
      rsum[r] = s;
    }
    // write P (unnormalized) bf16 -> p_lds [16][264]
    #pragma unroll
    for (int n = 0; n < 16; ++n)
      #pragma unroll
      for (int r = 0; r < 4; ++r)
        p_lds[(g * 4 + r) * 264 + n * 16 + c] = (bf16_t)s2[n][r];
    // O_img = P @ Vip^T
    #pragma unroll
    for (int n = 0; n < 4; ++n) oi[n] = (f32x4){0.f, 0.f, 0.f, 0.f};
    const bf16_t* vp = Vipt + (size_t)bh * 64 * 256 + (size_t)c * 256 + g * 8;
    #pragma unroll
    for (int kt = 0; kt < 8; ++kt) {
      bf16x8 pa = *(const bf16x8*)&p_lds[c * 264 + kt * 32 + g * 8];
      #pragma unroll
      for (int n = 0; n < 4; ++n) {
        bf16x8 bv = *(const bf16x8*)(vp + (size_t)n * 16 * 256 + kt * 32);
        oi[n] = MFMA16(pa, bv, oi[n]);
      }
    }
    float coef = tanhf(alpha[0]) + 1.0f;
    #pragma unroll
    for (int r = 0; r < 4; ++r) inv_si[r] = coef / rsum[r];
  }

  // ================= text attention with rel-pos =================
  f32x4 ot[4];
  float inv_st[4];
  {
    // T = Q @ Rk_slice^T  (N = 144, slice base u = 960 - i0)
    f32x4 ta[9];
    #pragma unroll
    for (int n = 0; n < 9; ++n) ta[n] = (f32x4){0.f, 0.f, 0.f, 0.f};
    const bf16_t* rp = Rkb + (size_t)(960 - i0 + c) * DIMH + g * 8;
    #pragma unroll
    for (int n = 0; n < 9; ++n) {
      bf16x8 b0 = *(const bf16x8*)(rp + n * 16 * DIMH);
      bf16x8 b1 = *(const bf16x8*)(rp + n * 16 * DIMH + 32);
      ta[n] = MFMA16(qa[0], b0, ta[n]);
      ta[n] = MFMA16(qa[1], b1, ta[n]);
    }
    // S = Q @ K_text^T (N = 80)
    f32x4 s[5];
    #pragma unroll
    for (int n = 0; n < 5; ++n) s[n] = (f32x4){0.f, 0.f, 0.f, 0.f};
    const bf16_t* kp = Kb + ((size_t)(b * TEXTLEN + c)) * DMODEL + h * DIMH + g * 8;
    #pragma unroll
    for (int n = 0; n < 5; ++n) {
      bf16x8 b0 = *(const bf16x8*)(kp + (size_t)n * 16 * DMODEL);
      bf16x8 b1 = *(const bf16x8*)(kp + (size_t)n * 16 * DMODEL + 32);
      s[n] = MFMA16(qa[0], b0, s[n]);
      s[n] = MFMA16(qa[1], b1, s[n]);
    }
    // T accs -> t_lds [16][148] f32
    #pragma unroll
    for (int n = 0; n < 9; ++n)
      #pragma unroll
      for (int r = 0; r < 4; ++r)
        t_lds[(g * 4 + r) * 148 + n * 16 + c] = ta[n][r];
    // combine S + sheared T, mask j >= 77
    float st[5][4];
    #pragma unroll
    for (int n = 0; n < 5; ++n)
      #pragma unroll
      for (int r = 0; r < 4; ++r) {
        int row = g * 4 + r;
        int il = w * 16 + row;
        int j = n * 16 + c;
        float v = s[n][r] + t_lds[row * 148 + j + 63 - il];
        st[n][r] = (j < TEXTLEN) ? v : -1e30f;
      }
    float rmax[4], rsum[4];
    #pragma unroll
    for (int r = 0; r < 4; ++r) {
      float m = st[0][r];
      #pragma unroll
      for (int n = 1; n < 5; ++n) m = fmaxf(m, st[n][r]);
      m = fmaxf(m, __shfl_xor(m, 1));
      m = fmaxf(m, __shfl_xor(m, 2));
      m = fmaxf(m, __shfl_xor(m, 4));
      m = fmaxf(m, __shfl_xor(m, 8));
      rmax[r] = m;
    }
    #pragma unroll
    for (int r = 0; r < 4; ++r) {
      float ssum = 0.f;
      #pragma unroll
      for (int n = 0; n < 5; ++n) {
        float p = exp2f((st[n][r] - rmax[r]) * SCALE_LOG2E);
        st[n][r] = p;
        ssum += p;
      }
      ssum += __shfl_xor(ssum, 1);
      ssum += __shfl_xor(ssum, 2);
      ssum += __shfl_xor(ssum, 4);
      ssum += __shfl_xor(ssum, 8);
      rsum[r] = ssum;
    }
    // zero P_cat region [16][232] (covers 4096 elems; buffer holds 4736)
    {
      bf16x8 zv;
      #pragma unroll
      for (int e = 0; e < 8; ++e) zv[e] = (bf16_t)0.f;
      #pragma unroll
      for (int z = 0; z < 8; ++z)
        *(bf16x8*)&p_lds[(z * 64 + lane) * 8] = zv;
    }
    // scatter P: sheared (cols [0,140)) + plain (cols 144+j)
    #pragma unroll
    for (int n = 0; n < 5; ++n)
      #pragma unroll
      for (int r = 0; r < 4; ++r) {
        int row = g * 4 + r;
        int il = w * 16 + row;
        int j = n * 16 + c;
        if (j < TEXTLEN) {
          bf16_t pb = (bf16_t)st[n][r];
          p_lds[row * 232 + j + 63 - il] = pb;
          p_lds[row * 232 + 144 + j] = pb;
        }
      }
    // O_text = [P' | P] @ [Rv_slice ; V]   (K = 224)
    #pragma unroll
    for (int n = 0; n < 4; ++n) ot[n] = (f32x4){0.f, 0.f, 0.f, 0.f};
    const bf16_t* vtp = Vt + (size_t)bh * 64 * 80 + (size_t)c * 80;
    const bf16_t* rvp = RvT + (size_t)c * 2048 + (960 - i0);
    #pragma unroll
    for (int kt = 0; kt < 7; ++kt) {
      bf16x8 pa = *(const bf16x8*)&p_lds[c * 232 + kt * 32 + g * 8];
      int tc = kt * 32 + g * 8;
      #pragma unroll
      for (int n = 0; n < 4; ++n) {
        const bf16_t* bp = (tc < 144)
            ? (rvp + (size_t)n * 16 * 2048 + tc)
            : (vtp + (size_t)n * 16 * 80 + (tc - 144));
        bf16x8 bv = *(const bf16x8*)bp;
        ot[n] = MFMA16(pa, bv, ot[n]);
      }
    }
    #pragma unroll
    for (int r = 0; r < 4; ++r) inv_st[r] = 1.0f / rsum[r];
  }

  // ================= combine + store =================
  bf16_t* op = Ob + ((size_t)(b * SEQ + iw)) * DMODEL + h * DIMH;
  #pragma unroll
  for (int n = 0; n < 4; ++n)
    #pragma unroll
    for (int r = 0; r < 4; ++r) {
      int row = g * 4 + r;
      int d = n * 16 + c;
      float v = ot[n][r] * inv_st[r] + oi[n][r] * inv_si[r];
      op[(size_t)row * DMODEL + d] = (bf16_t)v;
    }
}

// ---------------------------------------------------------------- launch
extern "C" void kernel_launch(void* const* d_in, const int* in_sizes, int n_in,
                              void* d_out, int out_size, void* d_ws, size_t ws_size,
                              hipStream_t stream)
{
  const float* x     = (const float*)d_in[0];
  const float* ctx   = (const float*)d_in[1];
  const float* W_q   = (const float*)d_in[2];
  const float* W_k   = (const float*)d_in[3];
  const float* W_v   = (const float*)d_in[4];
  const float* W_kip = (const float*)d_in[5];
  const float* W_vip = (const float*)d_in[6];
  const float* rel_k = (const float*)d_in[7];
  const float* rel_v = (const float*)d_in[8];
  const float* W_out = (const float*)d_in[9];
  const float* b_out = (const float*)d_in[10];
  const float* alpha = (const float*)d_in[11];

  // workspace carve
  char* ws = (char*)d_ws;
  bf16_t* Xb   = (bf16_t*)(ws + 0);            // 32768x1024 bf16 (64MB), reused as Ob
  bf16_t* Qb   = (bf16_t*)(ws + 67108864);     // 32768x1024 bf16 (64MB)
  bf16_t* CtxT = (bf16_t*)(ws + 134217728);    // 2560x1024  bf16 (5MB)
  bf16_t* CtxI = (bf16_t*)(ws + 139460608);    // 8192x1024  bf16 (16MB)
  bf16_t* WTs  = (bf16_t*)(ws + 156237824);    // 6 x 1024x1024 bf16 (12MB)
  bf16_t* WqT   = WTs + 0 * 1048576;
  bf16_t* WkT   = WTs + 1 * 1048576;
  bf16_t* WvT   = WTs + 2 * 1048576;
  bf16_t* WkipT = WTs + 3 * 1048576;
  bf16_t* WvipT = WTs + 4 * 1048576;
  bf16_t* WoutT = WTs + 5 * 1048576;
  bf16_t* Ob = Xb;

  // d_out scratch carve (dead before final GEMM writes d_out)
  char* dob = (char*)d_out;
  bf16_t* Kip  = (bf16_t*)(dob + 0);           // 8192x1024 bf16 (16MB)
  bf16_t* Vip  = (bf16_t*)(dob + 16777216);    // 16MB
  bf16_t* Kb   = (bf16_t*)(dob + 33554432);    // 2560x1024 bf16 (5MB)
  bf16_t* Vb   = (bf16_t*)(dob + 38797312);    // 5MB
  bf16_t* Vt   = (bf16_t*)(dob + 44040192);    // 512x64x80 bf16 (5MB)
  bf16_t* Vipt = (bf16_t*)(dob + 49283072);    // 512x64x256 bf16 (16MB)
  bf16_t* Rkb  = (bf16_t*)(dob + 66060288);    // 2048x64 bf16 (256KB)
  bf16_t* RvT  = (bf16_t*)(dob + 66322432);    // 64x2048 bf16 (256KB)

  // 1) converts / transposes
  k_cvt_x<<<16384, 256, 0, stream>>>(x, Xb);
  k_cvt_ctx<<<BATCH * CTXLEN, 128, 0, stream>>>(ctx, CtxT, CtxI);
  dim3 tb(32, 8), tg(32, 32);
  k_transpose_w<<<tg, tb, 0, stream>>>(W_q,   WqT);
  k_transpose_w<<<tg, tb, 0, stream>>>(W_k,   WkT);
  k_transpose_w<<<tg, tb, 0, stream>>>(W_v,   WvT);
  k_transpose_w<<<tg, tb, 0, stream>>>(W_kip, WkipT);
  k_transpose_w<<<tg, tb, 0, stream>>>(W_vip, WvipT);
  k_transpose_w<<<tg, tb, 0, stream>>>(W_out, WoutT);
  k_cvt_relk<<<64, 256, 0, stream>>>(rel_k, Rkb);
  k_cvt_relvT<<<64, 256, 0, stream>>>(rel_v, RvT);

  // 2) projections (bf16 outputs)
  k_gemm<0><<<dim3(256, 8), 256, 0, stream>>>(Xb,   WqT,   (void*)Qb,  nullptr, 32768, 1024, 1024);
  k_gemm<0><<<dim3(20, 8),  256, 0, stream>>>(CtxT, WkT,   (void*)Kb,  nullptr, 2560,  1024, 1024);
  k_gemm<0><<<dim3(20, 8),  256, 0, stream>>>(CtxT, WvT,   (void*)Vb,  nullptr, 2560,  1024, 1024);
  k_gemm<0><<<dim3(64, 8),  256, 0, stream>>>(CtxI, WkipT, (void*)Kip, nullptr, 8192,  1024, 1024);
  k_gemm<0><<<dim3(64, 8),  256, 0, stream>>>(CtxI, WvipT, (void*)Vip, nullptr, 8192,  1024, 1024);

  // 3) V transposes
  k_vtrans<TEXTLEN, 80><<<2 * 512, 256, 0, stream>>>(Vb, Vt);
  k_vtrans<IMGLEN, 256><<<4 * 512, 256, 0, stream>>>(Vip, Vipt);

  // 4) flash attention (text+rel and IP) -> Ob bf16
  k_flash<<<dim3(16, 512), 256, 0, stream>>>(Qb, Kb, Kip, Vt, Vipt, Rkb, RvT, alpha, Ob);

  // 5) output projection + bias -> d_out (f32)
  k_gemm<2><<<dim3(256, 8), 256, 0, stream>>>(Ob, WoutT, d_out, b_out, 32768, 1024, 1024);
}